// Round 10
// baseline (853.998 us; speedup 1.0000x reference)
//
#include <hip/hip_runtime.h>
#include <hip/hip_fp16.h>
#include <cstdint>

typedef int v4i __attribute__((ext_vector_type(4)));

#define AS1C(p) ((const __attribute__((address_space(1))) void*)(p))
#define AS3(p)  ((__attribute__((address_space(3))) void*)(p))

// ---------------------------------------------------------------------------
// Fused per-row symmetric int8 quantization (row-major outputs, r7 version).
// Single pass — the 16 KB row lives in 16 VGPRs between absmax and quantize.
// ---------------------------------------------------------------------------
__global__ __launch_bounds__(256) void quant_fused(const float* __restrict__ X,
                                                   const float* __restrict__ W,
                                                   int8_t* __restrict__ Xq,
                                                   int8_t* __restrict__ Wq,
                                                   float* __restrict__ a_scale,
                                                   float* __restrict__ w_scale) {
    const int row = blockIdx.x;
    const bool isW = row >= 8192;
    const int r = isW ? row - 8192 : row;
    const float* src = (isW ? W : X) + (size_t)r * 4096;
    int8_t* dst = isW ? (Wq + (size_t)r * 4096) : (Xq + (size_t)r * 4096);
    float* scp = (isW ? w_scale : a_scale) + r;

    const float4* xv = (const float4*)src;
    const int tid = threadIdx.x;

    float4 v[4];
#pragma unroll
    for (int j = 0; j < 4; ++j) v[j] = xv[tid + (j << 8)];

    float m = 0.0f;
#pragma unroll
    for (int j = 0; j < 4; ++j) {
        m = fmaxf(m, fmaxf(fmaxf(fabsf(v[j].x), fabsf(v[j].y)),
                           fmaxf(fabsf(v[j].z), fabsf(v[j].w))));
    }
    for (int off = 32; off > 0; off >>= 1)
        m = fmaxf(m, __shfl_xor(m, off, 64));

    __shared__ float wmax[4];
    __shared__ float s_sc;
    const int lane = tid & 63;
    const int wv = tid >> 6;
    if (lane == 0) wmax[wv] = m;
    __syncthreads();
    if (tid == 0) {
        float mm = fmaxf(fmaxf(wmax[0], wmax[1]), fmaxf(wmax[2], wmax[3]));
        float sc = mm / 127.0f;
        *scp = sc;
        s_sc = sc;
    }
    __syncthreads();
    const float sc = s_sc;

    char4* qv = (char4*)dst;
#pragma unroll
    for (int j = 0; j < 4; ++j) {
        char4 q;
        q.x = (signed char)(int)rintf(v[j].x / sc);
        q.y = (signed char)(int)rintf(v[j].y / sc);
        q.z = (signed char)(int)rintf(v[j].z / sc);
        q.w = (signed char)(int)rintf(v[j].w / sc);
        qv[tid + (j << 8)] = q;
    }
}

// ---------------------------------------------------------------------------
// int8 GEMM, 256x256 block tile, 256 threads = 4 waves in 2x2, per-wave
// 128x128 (8x8 accumulator fragments = 256 VGPRs).
// WHY: the r3-r9 ~52% MfmaUtil plateau was the operand-reuse ratio of the
// 128x64 wave tile — 12 ds_read_b128 per 32 MFMA put LDS demand (~1400
// cyc/tile) above the MFMA pipe (1306 cyc); block-lockstep waves then
// alternate pipes and cap at ~50% no matter the schedule. 128x128 waves
// read 16 frags per 64 MFMA (2.7x more MACs/LDS-byte): per-CU LDS demand
// 2260 cyc/tile-pair < MFMA 2614 — compute-bound even with bulk
// alternation. LDS = 2 x 32 KiB double-buffer (64 KiB) -> TWO independent
// blocks/CU whose un-synchronized schedules anti-phase naturally (m114),
// covering each other's vmcnt-drain and ds_read phases.
// Schedule: simple 2-phase — STAGE(next) ; ds_read(cur) ; 64 MFMA ;
// vmcnt(0)+barrier. No sched_barrier fences (m141), setprio around MFMA.
// Ring audit: STAGE at kt writes buf^1 (tile kt-1, reads lgkm-drained
// before kt-1's MFMAs which precede the end-of-(kt-1) barrier); end-of-kt
// vmcnt(0)+barrier makes tile kt+1 visible block-wide before its reads.
// ---------------------------------------------------------------------------
__global__ __launch_bounds__(256, 2) void gemm_i8(const int8_t* __restrict__ Aq,
                                                  const int8_t* __restrict__ Bq,
                                                  const float* __restrict__ a_scale,
                                                  const float* __restrict__ w_scale,
                                                  float* __restrict__ out) {
    extern __shared__ __align__(16) int8_t smem[];  // 2 x (A 16K | B 16K)

    const int K = 4096;
    const int bid = blockIdx.x;
    const int wg  = (bid & 7) * 64 + (bid >> 3);  // bijective: 512 = 8 x 64
    const int n0 = (wg & 15) * 256;
    const int m0 = (wg >> 4) * 256;

    const int tid  = threadIdx.x;
    const int lane = tid & 63;
    const int wid  = tid >> 6;   // 0..3
    const int wm   = wid >> 1;   // 0..1 -> M offset wm*128
    const int wn   = wid & 1;    // 0..1 -> N offset wn*128

    // fragment read offsets (64-B rows, 16-B-chunk XOR swizzle; row bits 1-2)
    const int rsel  = lane & 15;
    const int kswz  = ((lane >> 4) << 4) ^ (((rsel >> 1) & 3) << 4);
    const int abase = (wm * 128 + rsel) * 64 + kswz;
    const int bbase = 16384 + (wn * 128 + rsel) * 64 + kswz;

    // staging: 256 thr x 16 B = 4 KB/issue = 64 rows; 4 issues per operand
    const int strow = tid >> 2;                       // 0..63
    const int stcol = ((tid & 3) << 4) ^ (((strow >> 1) & 3) << 4);
    const int8_t* gA = Aq + (size_t)(m0 + strow) * K + stcol;
    const int8_t* gB = Bq + (size_t)(n0 + strow) * K + stcol;
    const int ldsst = wid * 1024;  // + lane*16 by HW

    v4i acc[8][8] = {};  // 256 VGPRs

#define STAGE(buf, kt) do {                                                          \
    int8_t* _d = smem + (buf) * 32768;                                               \
    const int8_t* _a = gA + (size_t)(kt) * 64;                                       \
    const int8_t* _b = gB + (size_t)(kt) * 64;                                       \
    _Pragma("unroll")                                                                \
    for (int i = 0; i < 4; ++i) {                                                    \
        __builtin_amdgcn_global_load_lds(AS1C(_a + (size_t)i * 64 * K),              \
                                         AS3(_d + i * 4096 + ldsst), 16, 0, 0);      \
        __builtin_amdgcn_global_load_lds(AS1C(_b + (size_t)i * 64 * K),              \
                                         AS3(_d + 16384 + i * 4096 + ldsst), 16, 0, 0); \
    }                                                                                \
  } while (0)

#define KSTEP(u, kt2) do {                                                           \
    const int kt  = (kt2) + (u);                                                     \
    const int8_t* bufc = smem + (u) * 32768;                                         \
    const int ktp = (kt + 1 < 64) ? kt + 1 : 63;  /* dead re-stage at tail */        \
    STAGE((u) ^ 1, ktp);                                                             \
    v4i aF[8], bF[8];                                                                \
    _Pragma("unroll")                                                                \
    for (int mt = 0; mt < 8; ++mt) aF[mt] = *(const v4i*)(bufc + abase + mt * 1024); \
    _Pragma("unroll")                                                                \
    for (int nt = 0; nt < 8; ++nt) bF[nt] = *(const v4i*)(bufc + bbase + nt * 1024); \
    __builtin_amdgcn_s_setprio(1);                                                   \
    _Pragma("unroll")                                                                \
    for (int mt = 0; mt < 8; ++mt)                                                   \
        _Pragma("unroll")                                                            \
        for (int nt = 0; nt < 8; ++nt)                                               \
            acc[mt][nt] = __builtin_amdgcn_mfma_i32_16x16x64_i8(                     \
                aF[mt], bF[nt], acc[mt][nt], 0, 0, 0);                               \
    __builtin_amdgcn_s_setprio(0);                                                   \
    asm volatile("s_waitcnt vmcnt(0)" ::: "memory");                                 \
    __builtin_amdgcn_s_barrier();                                                    \
  } while (0)

    // ---- prologue: stage tile 0 into buf 0
    STAGE(0, 0);
    asm volatile("s_waitcnt vmcnt(0)" ::: "memory");
    __builtin_amdgcn_s_barrier();

    for (int kt2 = 0; kt2 < 64; kt2 += 2) {
        KSTEP(0, kt2);
        KSTEP(1, kt2);
    }

    // epilogue: C/D layout col = lane&15 (N), row = (lane>>4)*4 + reg (M)
    const int r0  = (lane >> 4) << 2;
    const int col = lane & 15;
#pragma unroll
    for (int mt = 0; mt < 8; ++mt) {
        const int tbase = m0 + wm * 128 + mt * 16 + r0;
        float as[4];
#pragma unroll
        for (int r = 0; r < 4; ++r) as[r] = a_scale[tbase + r];
#pragma unroll
        for (int nt = 0; nt < 8; ++nt) {
            const int o = n0 + wn * 128 + nt * 16 + col;
            const float wsc = w_scale[o];
#pragma unroll
            for (int r = 0; r < 4; ++r) {
                float v = (float)acc[mt][nt][r] * as[r] * wsc;
                out[(size_t)(tbase + r) * 4096 + o] = __half2float(__float2half_rn(v));
            }
        }
    }
#undef KSTEP
#undef STAGE
}

extern "C" void kernel_launch(void* const* d_in, const int* in_sizes, int n_in,
                              void* d_out, int out_size, void* d_ws, size_t ws_size,
                              hipStream_t stream) {
    const float* input_act = (const float*)d_in[0];  // [4,2048,4096] = [8192,4096]
    const float* weight    = (const float*)d_in[1];  // [4096,4096]
    float* out = (float*)d_out;

    const int K = 4096, O = 4096, T = 8192;

    int8_t* x_q = (int8_t*)d_ws;
    int8_t* w_q = x_q + (size_t)T * K;
    float* a_scale = (float*)(w_q + (size_t)O * K);
    float* w_scale = a_scale + T;

    static bool attr_done = false;
    if (!attr_done) {
        hipFuncSetAttribute(reinterpret_cast<const void*>(gemm_i8),
                            hipFuncAttributeMaxDynamicSharedMemorySize, 65536);
        attr_done = true;
    }

    quant_fused<<<T + O, 256, 0, stream>>>(input_act, weight, x_q, w_q,
                                           a_scale, w_scale);

    dim3 grid(512);  // (8192/256) x (4096/256), XCD-swizzled in-kernel
    gemm_i8<<<grid, 256, 65536, stream>>>(x_q, w_q, a_scale, w_scale, out);
}

// Round 11
// 194.869 us; speedup vs baseline: 4.3824x; 4.3824x over previous
//
#include <hip/hip_runtime.h>
#include <hip/hip_fp16.h>
#include <cstdint>

typedef int v4i __attribute__((ext_vector_type(4)));

#define AS1C(p) ((const __attribute__((address_space(1))) void*)(p))
#define AS3(p)  ((__attribute__((address_space(3))) void*)(p))

// ---------------------------------------------------------------------------
// Fused per-row symmetric int8 quantization (row-major outputs, r7 version).
// Single pass — the 16 KB row lives in 16 VGPRs between absmax and quantize.
// ---------------------------------------------------------------------------
__global__ __launch_bounds__(256) void quant_fused(const float* __restrict__ X,
                                                   const float* __restrict__ W,
                                                   int8_t* __restrict__ Xq,
                                                   int8_t* __restrict__ Wq,
                                                   float* __restrict__ a_scale,
                                                   float* __restrict__ w_scale) {
    const int row = blockIdx.x;
    const bool isW = row >= 8192;
    const int r = isW ? row - 8192 : row;
    const float* src = (isW ? W : X) + (size_t)r * 4096;
    int8_t* dst = isW ? (Wq + (size_t)r * 4096) : (Xq + (size_t)r * 4096);
    float* scp = (isW ? w_scale : a_scale) + r;

    const float4* xv = (const float4*)src;
    const int tid = threadIdx.x;

    float4 v[4];
#pragma unroll
    for (int j = 0; j < 4; ++j) v[j] = xv[tid + (j << 8)];

    float m = 0.0f;
#pragma unroll
    for (int j = 0; j < 4; ++j) {
        m = fmaxf(m, fmaxf(fmaxf(fabsf(v[j].x), fabsf(v[j].y)),
                           fmaxf(fabsf(v[j].z), fabsf(v[j].w))));
    }
    for (int off = 32; off > 0; off >>= 1)
        m = fmaxf(m, __shfl_xor(m, off, 64));

    __shared__ float wmax[4];
    __shared__ float s_sc;
    const int lane = tid & 63;
    const int wv = tid >> 6;
    if (lane == 0) wmax[wv] = m;
    __syncthreads();
    if (tid == 0) {
        float mm = fmaxf(fmaxf(wmax[0], wmax[1]), fmaxf(wmax[2], wmax[3]));
        float sc = mm / 127.0f;
        *scp = sc;
        s_sc = sc;
    }
    __syncthreads();
    const float sc = s_sc;

    char4* qv = (char4*)dst;
#pragma unroll
    for (int j = 0; j < 4; ++j) {
        char4 q;
        q.x = (signed char)(int)rintf(v[j].x / sc);
        q.y = (signed char)(int)rintf(v[j].y / sc);
        q.z = (signed char)(int)rintf(v[j].z / sc);
        q.w = (signed char)(int)rintf(v[j].w / sc);
        qv[tid + (j << 8)] = q;
    }
}

// ---------------------------------------------------------------------------
// int8 GEMM, 256x128 block tile, 256 threads = 4 waves (2M x 2N), per-wave
// 128x64 (acc[8][4] = 128 regs — PROVEN to fit: r6/r7 ran 120-124 VGPR).
// WHY THIS SHAPE: r3-r7 showed the 8-wave 1-block/CU structure caps at ~52%
// MfmaUtil — barrier-locked waves alternate between the LDS port (~1400
// cyc/tile) and MFMA pipe (~1306), and no intra-block schedule overlapped
// them. r10 showed 256-reg accumulators spill. This config gets overlap the
// proven way (m114): LDS = 2 x (A 16K + B 8K) = 48 KiB and 256 threads ->
// TWO INDEPENDENT blocks/CU (one wave per SIMD each); un-synchronized
// blocks anti-phase so one block's MFMA covers the other's ds_read/drain.
// __launch_bounds__(256,2) caps VGPR at 256 (acc 128 + 12 frags 48 + addr).
// Schedule: T3-minimum 2-phase — STAGE(next); ds_read(cur); MFMA@prio1;
// vmcnt(0)+barrier. Cross-block concurrency replaces reg-double-buffering.
// Ring audit: STAGE at kt targets buf holding kt-1, whose reads all
// completed before the end-of-(kt-1) barrier; end-of-kt vmcnt(0)+barrier
// makes kt+1's LDS visible block-wide before any wave reads it.
// ---------------------------------------------------------------------------
__global__ __launch_bounds__(256, 2) void gemm_i8(const int8_t* __restrict__ Aq,
                                                  const int8_t* __restrict__ Bq,
                                                  const float* __restrict__ a_scale,
                                                  const float* __restrict__ w_scale,
                                                  float* __restrict__ out) {
    extern __shared__ __align__(16) int8_t smem[];  // 2 x (A 16K | B 8K)

    const int K = 4096;
    const int bid = blockIdx.x;
    const int wg  = (bid & 7) * 128 + (bid >> 3);  // bijective: 1024 = 8 x 128
    const int n0 = (wg & 31) * 128;   // 32 N-blocks
    const int m0 = (wg >> 5) * 256;   // 32 M-blocks

    const int tid  = threadIdx.x;
    const int lane = tid & 63;
    const int wid  = tid >> 6;   // 0..3 (= SIMD id)
    const int wm   = wid >> 1;   // 0..1 -> M offset wm*128
    const int wn   = wid & 1;    // 0..1 -> N offset wn*64

    // fragment read offsets (64-B rows, 16-B-chunk XOR swizzle on row bits 1-2)
    const int rsel  = lane & 15;
    const int kswz  = ((lane >> 4) << 4) ^ (((rsel >> 1) & 3) << 4);
    const int abase = (wm * 128 + rsel) * 64 + kswz;
    const int bbase = 16384 + (wn * 64 + rsel) * 64 + kswz;

    // staging: 256 thr x 16 B = 4 KB/issue = 64 rows; pre-swizzled source col
    const int strow = tid >> 2;                       // 0..63
    const int stcol = ((tid & 3) << 4) ^ (((strow >> 1) & 3) << 4);
    const int8_t* gA = Aq + (size_t)(m0 + strow) * K + stcol;
    const int8_t* gB = Bq + (size_t)(n0 + strow) * K + stcol;
    const int ldsst = wid * 1024;  // + lane*16 by HW

    v4i acc[8][4] = {};  // 128 regs

#define STAGE(buf, kt) do {                                                          \
    int8_t* _d = smem + (buf) * 24576;                                               \
    const int8_t* _a = gA + (size_t)(kt) * 64;                                       \
    const int8_t* _b = gB + (size_t)(kt) * 64;                                       \
    _Pragma("unroll")                                                                \
    for (int i = 0; i < 4; ++i)                                                      \
        __builtin_amdgcn_global_load_lds(AS1C(_a + (size_t)i * 64 * K),              \
                                         AS3(_d + i * 4096 + ldsst), 16, 0, 0);      \
    _Pragma("unroll")                                                                \
    for (int i = 0; i < 2; ++i)                                                      \
        __builtin_amdgcn_global_load_lds(AS1C(_b + (size_t)i * 64 * K),              \
                                         AS3(_d + 16384 + i * 4096 + ldsst), 16, 0, 0); \
  } while (0)

#define KSTEP(u, kt2) do {                                                           \
    const int kt  = (kt2) + (u);                                                     \
    const int8_t* bufc = smem + (u) * 24576;                                         \
    const int ktp = (kt + 1 < 64) ? kt + 1 : 63;  /* dead re-stage at tail */        \
    STAGE((u) ^ 1, ktp);                                                             \
    v4i aF[8], bF[4];                                                                \
    _Pragma("unroll")                                                                \
    for (int mt = 0; mt < 8; ++mt) aF[mt] = *(const v4i*)(bufc + abase + mt * 1024); \
    _Pragma("unroll")                                                                \
    for (int nt = 0; nt < 4; ++nt) bF[nt] = *(const v4i*)(bufc + bbase + nt * 1024); \
    __builtin_amdgcn_s_setprio(1);                                                   \
    _Pragma("unroll")                                                                \
    for (int mt = 0; mt < 8; ++mt)                                                   \
        _Pragma("unroll")                                                            \
        for (int nt = 0; nt < 4; ++nt)                                               \
            acc[mt][nt] = __builtin_amdgcn_mfma_i32_16x16x64_i8(                     \
                aF[mt], bF[nt], acc[mt][nt], 0, 0, 0);                               \
    __builtin_amdgcn_s_setprio(0);                                                   \
    asm volatile("s_waitcnt vmcnt(0)" ::: "memory");                                 \
    __builtin_amdgcn_s_barrier();                                                    \
  } while (0)

    // ---- prologue: stage tile 0 into buf 0
    STAGE(0, 0);
    asm volatile("s_waitcnt vmcnt(0)" ::: "memory");
    __builtin_amdgcn_s_barrier();

    for (int kt2 = 0; kt2 < 64; kt2 += 2) {
        KSTEP(0, kt2);
        KSTEP(1, kt2);
    }

    // epilogue: C/D layout col = lane&15 (N), row = (lane>>4)*4 + reg (M)
    const int r0  = (lane >> 4) << 2;
    const int col = lane & 15;
#pragma unroll
    for (int mt = 0; mt < 8; ++mt) {
        const int tbase = m0 + wm * 128 + mt * 16 + r0;
        float as[4];
#pragma unroll
        for (int r = 0; r < 4; ++r) as[r] = a_scale[tbase + r];
#pragma unroll
        for (int nt = 0; nt < 4; ++nt) {
            const int o = n0 + wn * 64 + nt * 16 + col;
            const float wsc = w_scale[o];
#pragma unroll
            for (int r = 0; r < 4; ++r) {
                float v = (float)acc[mt][nt][r] * as[r] * wsc;
                out[(size_t)(tbase + r) * 4096 + o] = __half2float(__float2half_rn(v));
            }
        }
    }
#undef KSTEP
#undef STAGE
}

extern "C" void kernel_launch(void* const* d_in, const int* in_sizes, int n_in,
                              void* d_out, int out_size, void* d_ws, size_t ws_size,
                              hipStream_t stream) {
    const float* input_act = (const float*)d_in[0];  // [4,2048,4096] = [8192,4096]
    const float* weight    = (const float*)d_in[1];  // [4096,4096]
    float* out = (float*)d_out;

    const int K = 4096, O = 4096, T = 8192;

    int8_t* x_q = (int8_t*)d_ws;
    int8_t* w_q = x_q + (size_t)T * K;
    float* a_scale = (float*)(w_q + (size_t)O * K);
    float* w_scale = a_scale + T;

    static bool attr_done = false;
    if (!attr_done) {
        hipFuncSetAttribute(reinterpret_cast<const void*>(gemm_i8),
                            hipFuncAttributeMaxDynamicSharedMemorySize, 49152);
        attr_done = true;
    }

    quant_fused<<<T + O, 256, 0, stream>>>(input_act, weight, x_q, w_q,
                                           a_scale, w_scale);

    dim3 grid(1024);  // (8192/256) x (4096/128), XCD-swizzled in-kernel
    gemm_i8<<<grid, 256, 49152, stream>>>(x_q, w_q, a_scale, w_scale, out);
}